// Round 4
// baseline (9844.550 us; speedup 1.0000x reference)
//
#include <hip/hip_runtime.h>
#include <hip/hip_bf16.h>

typedef short  short8 __attribute__((ext_vector_type(8)));
typedef float  f32x4  __attribute__((ext_vector_type(4)));
using ushort = unsigned short;
using uint   = unsigned int;
using ull    = unsigned long long;

#define KP2 1280               // padded K: 1024 (h) + 256 (x pad)
#define XP  128                // bf16 x row stride
#define XPF 80                 // fp32 x row stride
#define AL  __ATOMIC_RELAXED
#define SC  __HIP_MEMORY_SCOPE_AGENT

__device__ __forceinline__ ushort f2bf(float f) {
    uint u = __float_as_uint(f);
    return (ushort)((u + 0x7fffu + ((u >> 16) & 1u)) >> 16);  // RNE
}
// async global->LDS, 16B/lane, aux=17 = sc0|sc1 (coherent, L2-bypass)
__device__ __forceinline__ void gld16(const void* g, void* l) {
    __builtin_amdgcn_global_load_lds(
        (const __attribute__((address_space(1))) uint*)g,
        (__attribute__((address_space(3))) uint*)l, 16, 0, 17);
}

// two-level grid barrier: 32 groups x 8 blocks -> root(32). No cache inv.
__device__ __forceinline__ void gridbar(uint* ctrs, uint* root, uint* gen, int blk) {
    __syncthreads();
    if (threadIdx.x == 0) {
        uint g = __hip_atomic_load(gen, AL, SC);
        uint* c = ctrs + (blk & 31) * 16;
        if (__hip_atomic_fetch_add(c, 1u, __ATOMIC_ACQ_REL, SC) == 7u) {
            __hip_atomic_store(c, 0u, AL, SC);
            if (__hip_atomic_fetch_add(root, 1u, __ATOMIC_ACQ_REL, SC) == 31u) {
                __hip_atomic_store(root, 0u, AL, SC);
                __hip_atomic_fetch_add(gen, 1u, __ATOMIC_RELEASE, SC);
            }
        }
        while (__hip_atomic_load(gen, AL, SC) == g) __builtin_amdgcn_s_sleep(1);
    }
    __syncthreads();
}

#define MFMA __builtin_amdgcn_mfma_f32_16x16x32_bf16
#define GRU_COMPUTE(AN, PREF)                                                     \
    _Pragma("unroll")                                                             \
    for (int kk = 0; kk < 4; ++kk) {                                              \
        short8 b0 = bq[kk][0], b1 = bq[kk][1], b2 = bq[kk][2];                    \
        if (PREF) {                                                               \
            const int off = ((st + 1) * 8 + wk * 4 + kk) * 32;                    \
            bq[kk][0] = *(const short8*)(bpr0 + off);                             \
            bq[kk][1] = *(const short8*)(bpr1 + off);                             \
            bq[kk][2] = *(const short8*)(bpr2 + off);                             \
        }                                                                         \
        const int g  = (wk * 4 + kk) * 4 + quad;                                  \
        const int ch = (g & 16) | ((g & 15) ^ l16);                               \
        const ushort* ap_ = ab + l16 * 256 + ch * 8;                              \
        short8 a0 = *(const short8*)(ap_);                                        \
        short8 a1 = *(const short8*)(ap_ + 4096);                                 \
        short8 a2 = *(const short8*)(ap_ + 8192);                                 \
        short8 a3 = *(const short8*)(ap_ + 12288);                                \
        accR[0] = MFMA(a0, b0, accR[0], 0, 0, 0);                                 \
        accZ[0] = MFMA(a0, b1, accZ[0], 0, 0, 0);                                 \
        AN[0]   = MFMA(a0, b2, AN[0],   0, 0, 0);                                 \
        accR[1] = MFMA(a1, b0, accR[1], 0, 0, 0);                                 \
        accZ[1] = MFMA(a1, b1, accZ[1], 0, 0, 0);                                 \
        AN[1]   = MFMA(a1, b2, AN[1],   0, 0, 0);                                 \
        accR[2] = MFMA(a2, b0, accR[2], 0, 0, 0);                                 \
        accZ[2] = MFMA(a2, b1, accZ[2], 0, 0, 0);                                 \
        AN[2]   = MFMA(a2, b2, AN[2],   0, 0, 0);                                 \
        accR[3] = MFMA(a3, b0, accR[3], 0, 0, 0);                                 \
        accZ[3] = MFMA(a3, b1, accZ[3], 0, 0, 0);                                 \
        AN[3]   = MFMA(a3, b2, AN[3],   0, 0, 0);                                 \
    }

__global__ __launch_bounds__(512, 2) void rnn_all(
    const float* __restrict__ enc,  const float* __restrict__ dec,
    const float* __restrict__ w_ih, const float* __restrict__ w_hh,
    const float* __restrict__ b_ih, const float* __restrict__ b_hh,
    const float* __restrict__ fc1_w, const float* __restrict__ fc1_b,
    const float* __restrict__ fc2_w, const float* __restrict__ fc2_b,
    float* __restrict__ out,
    uint* bar, ushort* wpack, ushort* w1p, ushort* frames, float* x0f,
    float* hf0, float* hf1, ushort* hbf0, ushort* hbf1,
    float* xfA, float* xfB, ushort* xbfA, ushort* xbfB,
    float* logit, ushort* zpad)
{
    __shared__ __align__(16) ushort ldsA[2][16384];   // 64 KB: dbuf 64x256 bf16
    const int t = threadIdx.x, blk = blockIdx.x;
    const uint gtid = blk * 512 + t;
    uint* ctrs = bar; uint* root = bar + 512; uint* gen = bar + 513;

    // ================= pack phase (grid-stride) =================
    for (uint i = gtid; i < 983040u; i += 131072u) {        // wpack [3072][1280]
        uint row = i / 320u, c4 = (i % 320u) * 4u;
        ushort4 o; ushort* po = (ushort*)&o;
#pragma unroll
        for (int e = 0; e < 4; ++e) {
            uint k = c4 + e; float v = 0.f;
            if (k < 1024u)      v = w_hh[(size_t)row * 1024u + k];
            else if (k < 1093u) v = w_ih[(size_t)row * 69u + (k - 1024u)];
            po[e] = f2bf(v);
        }
        *(ushort4*)(wpack + (size_t)row * KP2 + c4) = o;
    }
    for (uint i = gtid; i < 20480u; i += 131072u) {         // w1p [80][1024]
        uint row = i / 256u, c4 = (i % 256u) * 4u;
        ushort4 o; ushort* po = (ushort*)&o;
#pragma unroll
        for (int e = 0; e < 4; ++e)
            po[e] = (row < 69u) ? f2bf(fc1_w[(size_t)row * 1024u + c4 + e]) : (ushort)0;
        *(ushort4*)(w1p + (size_t)row * 1024u + c4) = o;
    }
    for (uint i = gtid; i < 2424832u; i += 131072u) {       // frames [74][1024][128]
        uint tf = i >> 15, b = (i >> 5) & 1023u, c4 = (i & 31u) * 4u;
        ushort4 o; ushort* po = (ushort*)&o;
#pragma unroll
        for (int e = 0; e < 4; ++e) {
            uint idx = c4 + e; float v = 0.f;
            if (idx < 69u)
                v = (tf < 50u) ? enc[((size_t)b * 50u + tf) * 69u + idx]
                               : dec[((size_t)b * 24u + (tf - 50u)) * 69u + idx];
            po[e] = f2bf(v);
        }
        *(ushort4*)(frames + (size_t)tf * 131072u + (size_t)b * XP + c4) = o;
    }
    for (uint i = gtid; i < 81920u; i += 131072u) {         // x0f [1024][80]
        uint b = i / 80u, c = i % 80u;
        x0f[i] = (c < 69u) ? enc[(size_t)b * 3450u + c] : 0.f;
    }
    for (uint i = gtid; i < 262144u; i += 131072u)          // hf0 = 0
        ((float4*)hf0)[i] = make_float4(0.f, 0.f, 0.f, 0.f);
    for (uint i = gtid; i < 524288u; i += 131072u)          // hbf0 = 0
        ((uint*)hbf0)[i] = 0u;
    for (uint i = gtid; i < 65536u; i += 131072u) { ((uint*)xbfA)[i] = 0u; ((uint*)xbfB)[i] = 0u; }
    for (uint i = gtid; i < 1024u; i += 131072u) logit[i] = fc2_b[0];
    for (uint i = gtid; i < 256u; i += 131072u) ((uint*)zpad)[i] = 0u;
    __syncthreads();
    if (t == 0) __threadfence();          // flush pack-phase stores (wbl2+inv, once)
    gridbar(ctrs, root, gen, blk);

    // ================= per-block constants =================
    const int xcd = blk & 7, idx = blk >> 3;
    const int bn = xcd * 2 + (idx & 1), bm = idx >> 1;     // XCD-resident wpack slice
    const int wave = t >> 6, lane = t & 63;
    const int wk = wave >> 2, wn = wave & 3;
    const int quad = lane >> 4, l16 = lane & 15;

    int hOff[4], xOff[4], ldsOff[4]; bool useX[4];
#pragma unroll
    for (int i = 0; i < 4; ++i) {                           // staging descriptors
        int c = (wave * 4 + i) * 64 + lane;
        int row = c >> 5, chunk = c & 31;
        int kb = chunk >> 4, j = chunk & 15;
        int gl = ((kb << 4) | (j ^ (row & 15))) * 8;
        int rowg = bm * 64 + row;
        hOff[i] = rowg * 1024 + gl;
        xOff[i] = rowg * XP + gl;
        useX[i] = (gl < 128);
        ldsOff[i] = (wave * 4 + i) * 512;
    }
    const int rowN = bn * 64 + wn * 16 + l16;
    const ushort* bpr0 = wpack + (size_t)rowN * KP2 + quad * 8;
    const ushort* bpr1 = bpr0 + (size_t)1024 * KP2;
    const ushort* bpr2 = bpr0 + (size_t)2048 * KP2;
    const float bir = b_ih[rowN],        bhr = b_hh[rowN];
    const float biz = b_ih[1024 + rowN], bhz = b_hh[1024 + rowN];
    const float bin_= b_ih[2048 + rowN], bhn = b_hh[2048 + rowN];
    const int wgid = blk * 8 + wave;                        // fc1 task id
    const ushort* fbp = w1p + (size_t)(((wgid >> 6) & 7) * 16 + l16) * 1024 + quad * 8;

    // ================= time loop =================
#pragma unroll 1
    for (int s = 0; s < 148; ++s) {
        const ushort* hsrc = (s & 1) ? hbf1 : hbf0;
        ushort*       hdst = (s & 1) ? hbf0 : hbf1;
        const float* hfsrc = (s & 1) ? hf1 : hf0;
        float*       hfdst = (s & 1) ? hf0 : hf1;
        const ushort* xsrc = (s < 74) ? frames + (size_t)s * 131072u
                           : (s == 74 ? frames : (((s - 75) & 1) ? xbfB : xbfA));

        f32x4 accR[4], accZ[4], accNH[4], accNI[4];
#pragma unroll
        for (int i = 0; i < 4; ++i) {
            accR[i] = (f32x4){0.f,0.f,0.f,0.f}; accZ[i] = (f32x4){0.f,0.f,0.f,0.f};
            accNH[i] = (f32x4){0.f,0.f,0.f,0.f}; accNI[i] = (f32x4){0.f,0.f,0.f,0.f};
        }
        short8 bq[4][3];
#pragma unroll
        for (int kk = 0; kk < 4; ++kk) {
            const int off = (wk * 4 + kk) * 32;
            bq[kk][0] = *(const short8*)(bpr0 + off);
            bq[kk][1] = *(const short8*)(bpr1 + off);
            bq[kk][2] = *(const short8*)(bpr2 + off);
        }
#pragma unroll
        for (int i = 0; i < 4; ++i)                          // stage 0 (pure h)
            gld16(hsrc + hOff[i], &ldsA[0][ldsOff[i]]);
        __syncthreads();

#pragma unroll 1
        for (int st = 0; st < 5; ++st) {
            if (st < 4) {                                    // stage st+1 into other buf
                const int st1 = st + 1;
#pragma unroll
                for (int i = 0; i < 4; ++i) {
                    const ushort* g = (st1 < 4) ? hsrc + hOff[i] + st1 * 256
                                    : (useX[i] ? xsrc + xOff[i] : zpad);
                    gld16(g, &ldsA[st1 & 1][ldsOff[i]]);
                }
            }
            const ushort* ab = &ldsA[st & 1][0];
            if (st < 4) { GRU_COMPUTE(accNH, 1) } else { GRU_COMPUTE(accNI, 0) }
            __syncthreads();
        }

        // cross-wk reduction via LDS
        f32x4* red = (f32x4*)&ldsA[0][0];
        const int rslot = wn * 64 + lane;
        if (wk == 1) {
#pragma unroll
            for (int mt = 0; mt < 4; ++mt) {
                red[mt * 256 + rslot]        = accR[mt];
                red[1024 + mt * 256 + rslot] = accZ[mt];
            }
        }
        __syncthreads();
        if (wk == 0) {
#pragma unroll
            for (int mt = 0; mt < 4; ++mt) {
                accR[mt] += red[mt * 256 + rslot];
                accZ[mt] += red[1024 + mt * 256 + rslot];
            }
        }
        __syncthreads();
        if (wk == 1) {
#pragma unroll
            for (int mt = 0; mt < 4; ++mt) {
                red[mt * 256 + rslot]        = accNH[mt];
                red[1024 + mt * 256 + rslot] = accNI[mt];
            }
        }
        __syncthreads();
        if (wk == 0) {
#pragma unroll
            for (int mt = 0; mt < 4; ++mt) {
                accNH[mt] += red[mt * 256 + rslot];
                accNI[mt] += red[1024 + mt * 256 + rslot];
            }
            // epilogue: gates; h out via agent-scope stores (coherent, no L2 dirty)
#pragma unroll
            for (int mt = 0; mt < 4; ++mt) {
#pragma unroll
                for (int r = 0; r < 4; ++r) {
                    const int m = bm * 64 + mt * 16 + quad * 4 + r;
                    float gr = accR[mt][r] + bir + bhr;
                    float gz = accZ[mt][r] + biz + bhz;
                    float rg = 1.f / (1.f + __expf(-gr));
                    float zg = 1.f / (1.f + __expf(-gz));
                    float nx = accNI[mt][r] + bin_ + rg * (accNH[mt][r] + bhn);
                    nx = fminf(30.f, fmaxf(-30.f, nx));
                    float e  = __expf(-2.f * nx);
                    float ng = (1.f - e) / (1.f + e);
                    float hp = __hip_atomic_load((float*)(hfsrc + (size_t)m * 1024 + rowN), AL, SC);
                    float hn = (1.f - zg) * ng + zg * hp;
                    __hip_atomic_store(hfdst + (size_t)m * 1024 + rowN, hn, AL, SC);
                    ushort hb = f2bf(hn);
                    int ob = __shfl_xor((int)hb, 1, 64);
                    if ((lane & 1) == 0)
                        __hip_atomic_store((uint*)(hdst + (size_t)m * 1024 + rowN),
                                           (uint)hb | ((uint)ob << 16), AL, SC);
                }
            }
        }
        gridbar(ctrs, root, gen, blk);

        if (s >= 74) {                                       // fc1 phase (decode)
            const int d = s - 74;
            const float* xprevf = (d == 0) ? x0f : (((d - 1) & 1) ? xfB : xfA);
            float*  xfout  = (d & 1) ? xfB : xfA;
            ushort* xbfout = (d & 1) ? xbfB : xbfA;
            if (wgid < 320) {                                // 64 mt x 5 nt tasks
                const int mt0 = (wgid & 63) * 16, nt = wgid >> 6;
                const ushort* ap = hdst + (size_t)(mt0 + l16) * 1024 + quad * 8;
                union { ull q[2]; short8 s8; } aw[8];
                short8 bw[8];
#pragma unroll
                for (int p = 0; p < 8; ++p) {
                    const ull* qp = (const ull*)(ap + p * 32);
                    aw[p].q[0] = __hip_atomic_load((ull*)qp, AL, SC);
                    aw[p].q[1] = __hip_atomic_load((ull*)qp + 1, AL, SC);
                    bw[p] = *(const short8*)(fbp + p * 32);
                }
                f32x4 facc = (f32x4){0.f, 0.f, 0.f, 0.f};
#pragma unroll
                for (int ks = 0; ks < 32; ++ks) {
                    short8 a = aw[ks & 7].s8, b = bw[ks & 7];
                    if (ks < 24) {
                        const ull* qp = (const ull*)(ap + (ks + 8) * 32);
                        aw[ks & 7].q[0] = __hip_atomic_load((ull*)qp, AL, SC);
                        aw[ks & 7].q[1] = __hip_atomic_load((ull*)qp + 1, AL, SC);
                        bw[ks & 7] = *(const short8*)(fbp + (ks + 8) * 32);
                    }
                    facc = MFMA(a, b, facc, 0, 0, 0);
                }
                const int jf = nt * 16 + l16;
                const bool jv = jf < 69;
                const float b1v = jv ? fc1_b[jf] : 0.f;
                const float w2v = jv ? fc2_w[d * 69 + jf] : 0.f;
#pragma unroll
                for (int r = 0; r < 4; ++r) {
                    const int m = mt0 + quad * 4 + r;
                    float o = facc[r] + xprevf[(size_t)m * XPF + jf] + b1v;
                    xfout[(size_t)m * XPF + jf] = o;
                    ushort xb = f2bf(o);
                    int ob = __shfl_xor((int)xb, 1, 64);
                    if ((l16 & 1) == 0)
                        __hip_atomic_store((uint*)(xbfout + (size_t)m * XP + jf),
                                           (uint)xb | ((uint)ob << 16), AL, SC);
                    float lp = w2v * o;
                    lp += __shfl_xor(lp, 8, 64);
                    lp += __shfl_xor(lp, 4, 64);
                    lp += __shfl_xor(lp, 2, 64);
                    lp += __shfl_xor(lp, 1, 64);
                    if (l16 == 0) atomicAdd(logit + m, lp);
                }
            }
            gridbar(ctrs, root, gen, blk);
        }
    }
    // ================= final =================
    if (blk == 0) {
        for (int i = t; i < 1024; i += 512) {
            float lg = __hip_atomic_load(logit + i, AL, SC);
            out[i] = 1.f / (1.f + __expf(-lg));
        }
    }
}

extern "C" void kernel_launch(void* const* d_in, const int* in_sizes, int n_in,
                              void* d_out, int out_size, void* d_ws, size_t ws_size,
                              hipStream_t stream)
{
    const float* enc   = (const float*)d_in[0];
    const float* dec   = (const float*)d_in[1];
    const float* w_ih  = (const float*)d_in[2];
    const float* w_hh  = (const float*)d_in[3];
    const float* b_ih  = (const float*)d_in[4];
    const float* b_hh  = (const float*)d_in[5];
    const float* fc1_w = (const float*)d_in[6];
    const float* fc1_b = (const float*)d_in[7];
    const float* fc2_w = (const float*)d_in[8];
    const float* fc2_b = (const float*)d_in[9];
    float* out = (float*)d_out;

    char* ws = (char*)d_ws;
    size_t off = 0;
    auto alloc = [&](size_t bytes) -> void* {
        void* p = ws + off; off += (bytes + 255) & ~(size_t)255; return p;
    };
    uint*   bar    = (uint*)  alloc(4096);
    ushort* wpack  = (ushort*)alloc((size_t)3072 * KP2 * 2);
    ushort* w1p    = (ushort*)alloc((size_t)80 * 1024 * 2);
    ushort* frames = (ushort*)alloc((size_t)74 * 1024 * XP * 2);
    float*  x0f    = (float*) alloc((size_t)1024 * XPF * 4);
    float*  hf0    = (float*) alloc((size_t)1024 * 1024 * 4);
    float*  hf1    = (float*) alloc((size_t)1024 * 1024 * 4);
    ushort* hbf0   = (ushort*)alloc((size_t)1024 * 1024 * 2);
    ushort* hbf1   = (ushort*)alloc((size_t)1024 * 1024 * 2);
    float*  xfA    = (float*) alloc((size_t)1024 * XPF * 4);
    float*  xfB    = (float*) alloc((size_t)1024 * XPF * 4);
    ushort* xbfA   = (ushort*)alloc((size_t)1024 * XP * 2);
    ushort* xbfB   = (ushort*)alloc((size_t)1024 * XP * 2);
    float*  logit  = (float*) alloc((size_t)1024 * 4);
    ushort* zpad   = (ushort*)alloc(1024);

    hipMemsetAsync(bar, 0, 4096, stream);
    rnn_all<<<256, 512, 0, stream>>>(enc, dec, w_ih, w_hh, b_ih, b_hh,
                                     fc1_w, fc1_b, fc2_w, fc2_b, out,
                                     bar, wpack, w1p, frames, x0f,
                                     hf0, hf1, hbf0, hbf1,
                                     xfA, xfB, xbfA, xbfB, logit, zpad);
}

// Round 5
// 8372.444 us; speedup vs baseline: 1.1758x; 1.1758x over previous
//
#include <hip/hip_runtime.h>
#include <hip/hip_bf16.h>

typedef short  short8 __attribute__((ext_vector_type(8)));
typedef float  f32x4  __attribute__((ext_vector_type(4)));
using ushort = unsigned short;
using uint   = unsigned int;

#define KP2 1280               // padded K: 1024 (h) + 256 (x pad)
#define XP  128                // bf16 x row stride
#define AL  __ATOMIC_RELAXED
#define SC  __HIP_MEMORY_SCOPE_AGENT

__device__ __forceinline__ ushort f2bf(float f) {
    uint u = __float_as_uint(f);
    return (ushort)((u + 0x7fffu + ((u >> 16) & 1u)) >> 16);  // RNE
}
// async global->LDS, 16B/lane, normal cached path (aux=0)
__device__ __forceinline__ void gld16(const void* g, void* l) {
    __builtin_amdgcn_global_load_lds(
        (const __attribute__((address_space(1))) uint*)g,
        (__attribute__((address_space(3))) uint*)l, 16, 0, 0);
}

// two-level grid barrier with agent release/acquire fences:
// release (buffer_wbl2) before arrive -> dirty L2 reaches MALL;
// acquire (buffer_inv) after leave -> subsequent plain loads refill from MALL.
__device__ __forceinline__ void gridbar(uint* ctrs, uint* root, uint* gen, int blk) {
    __syncthreads();                       // drains each wave's stores into L2
    __atomic_signal_fence(__ATOMIC_SEQ_CST);
    if (threadIdx.x == 0) {
        __builtin_amdgcn_fence(__ATOMIC_RELEASE, "agent");
        uint g = __hip_atomic_load(gen, AL, SC);
        uint* c = ctrs + (blk & 31) * 16;
        if (__hip_atomic_fetch_add(c, 1u, AL, SC) == 7u) {
            __hip_atomic_store(c, 0u, AL, SC);
            if (__hip_atomic_fetch_add(root, 1u, AL, SC) == 31u) {
                __hip_atomic_store(root, 0u, AL, SC);
                __hip_atomic_fetch_add(gen, 1u, AL, SC);
            }
        }
        while (__hip_atomic_load(gen, AL, SC) == g) __builtin_amdgcn_s_sleep(1);
        __builtin_amdgcn_fence(__ATOMIC_ACQUIRE, "agent");
    }
    __atomic_signal_fence(__ATOMIC_SEQ_CST);
    __syncthreads();
}

#define MFMA __builtin_amdgcn_mfma_f32_16x16x32_bf16
#define GRU_COMPUTE(AN, PREF)                                                     \
    _Pragma("unroll")                                                             \
    for (int kk = 0; kk < 4; ++kk) {                                              \
        short8 b0 = bq[kk][0], b1 = bq[kk][1], b2 = bq[kk][2];                    \
        if (PREF) {                                                               \
            const int off = ((st + 1) * 8 + wk * 4 + kk) * 32;                    \
            bq[kk][0] = *(const short8*)(bpr0 + off);                             \
            bq[kk][1] = *(const short8*)(bpr1 + off);                             \
            bq[kk][2] = *(const short8*)(bpr2 + off);                             \
        }                                                                         \
        const int g  = (wk * 4 + kk) * 4 + quad;                                  \
        const int ch = (g & 16) | ((g & 15) ^ l16);                               \
        const ushort* ap_ = ab + l16 * 256 + ch * 8;                              \
        short8 a0 = *(const short8*)(ap_);                                        \
        short8 a1 = *(const short8*)(ap_ + 4096);                                 \
        short8 a2 = *(const short8*)(ap_ + 8192);                                 \
        short8 a3 = *(const short8*)(ap_ + 12288);                                \
        accR[0] = MFMA(a0, b0, accR[0], 0, 0, 0);                                 \
        accZ[0] = MFMA(a0, b1, accZ[0], 0, 0, 0);                                 \
        AN[0]   = MFMA(a0, b2, AN[0],   0, 0, 0);                                 \
        accR[1] = MFMA(a1, b0, accR[1], 0, 0, 0);                                 \
        accZ[1] = MFMA(a1, b1, accZ[1], 0, 0, 0);                                 \
        AN[1]   = MFMA(a1, b2, AN[1],   0, 0, 0);                                 \
        accR[2] = MFMA(a2, b0, accR[2], 0, 0, 0);                                 \
        accZ[2] = MFMA(a2, b1, accZ[2], 0, 0, 0);                                 \
        AN[2]   = MFMA(a2, b2, AN[2],   0, 0, 0);                                 \
        accR[3] = MFMA(a3, b0, accR[3], 0, 0, 0);                                 \
        accZ[3] = MFMA(a3, b1, accZ[3], 0, 0, 0);                                 \
        AN[3]   = MFMA(a3, b2, AN[3],   0, 0, 0);                                 \
    }

__global__ __launch_bounds__(512) void rnn_all(
    const float* __restrict__ enc,  const float* __restrict__ dec,
    const float* __restrict__ w_ih, const float* __restrict__ w_hh,
    const float* __restrict__ b_ih, const float* __restrict__ b_hh,
    const float* __restrict__ fc1_w, const float* __restrict__ fc1_b,
    const float* __restrict__ fc2_w, const float* __restrict__ fc2_b,
    float* __restrict__ out,
    uint* bar, ushort* wpack, ushort* w1p, ushort* frames,
    ushort* hbf0, ushort* hbf1, ushort* xbfA, ushort* xbfB,
    float* logit, ushort* zpad)
{
    __shared__ __align__(16) ushort ldsA[2][16384];   // 64 KB: dbuf 64x256 bf16
    const int t = threadIdx.x, blk = blockIdx.x;
    const uint gtid = blk * 512 + t;
    uint* ctrs = bar; uint* root = bar + 512; uint* gen = bar + 513;

    // ================= pack phase (grid-stride) =================
    for (uint i = gtid; i < 983040u; i += 131072u) {        // wpack [3072][1280]
        uint row = i / 320u, c4 = (i % 320u) * 4u;
        ushort4 o; ushort* po = (ushort*)&o;
#pragma unroll
        for (int e = 0; e < 4; ++e) {
            uint k = c4 + e; float v = 0.f;
            if (k < 1024u)      v = w_hh[(size_t)row * 1024u + k];
            else if (k < 1093u) v = w_ih[(size_t)row * 69u + (k - 1024u)];
            po[e] = f2bf(v);
        }
        *(ushort4*)(wpack + (size_t)row * KP2 + c4) = o;
    }
    for (uint i = gtid; i < 20480u; i += 131072u) {         // w1p [80][1024]
        uint row = i / 256u, c4 = (i % 256u) * 4u;
        ushort4 o; ushort* po = (ushort*)&o;
#pragma unroll
        for (int e = 0; e < 4; ++e)
            po[e] = (row < 69u) ? f2bf(fc1_w[(size_t)row * 1024u + c4 + e]) : (ushort)0;
        *(ushort4*)(w1p + (size_t)row * 1024u + c4) = o;
    }
    for (uint i = gtid; i < 2424832u; i += 131072u) {       // frames [74][1024][128]
        uint tf = i >> 15, b = (i >> 5) & 1023u, c4 = (i & 31u) * 4u;
        ushort4 o; ushort* po = (ushort*)&o;
#pragma unroll
        for (int e = 0; e < 4; ++e) {
            uint idx = c4 + e; float v = 0.f;
            if (idx < 69u)
                v = (tf < 50u) ? enc[((size_t)b * 50u + tf) * 69u + idx]
                               : dec[((size_t)b * 24u + (tf - 50u)) * 69u + idx];
            po[e] = f2bf(v);
        }
        *(ushort4*)(frames + (size_t)tf * 131072u + (size_t)b * XP + c4) = o;
    }
    for (uint i = gtid; i < 524288u; i += 131072u)          // hbf0 = 0
        ((uint*)hbf0)[i] = 0u;
    for (uint i = gtid; i < 65536u; i += 131072u) { ((uint*)xbfA)[i] = 0u; ((uint*)xbfB)[i] = 0u; }
    for (uint i = gtid; i < 1024u; i += 131072u) logit[i] = fc2_b[0];
    for (uint i = gtid; i < 256u; i += 131072u) ((uint*)zpad)[i] = 0u;
    gridbar(ctrs, root, gen, blk);

    // ================= per-block constants =================
    const int xcd = blk & 7, idx = blk >> 3;
    const int bn = xcd * 2 + (idx & 1), bm = idx >> 1;     // XCD-resident wpack slice
    const int wave = t >> 6, lane = t & 63;
    const int wk = wave >> 2, wn = wave & 3;
    const int quad = lane >> 4, l16 = lane & 15;

    int hOff[4], xOff[4], ldsOff[4]; bool useX[4];
#pragma unroll
    for (int i = 0; i < 4; ++i) {                           // staging descriptors
        int c = (wave * 4 + i) * 64 + lane;
        int row = c >> 5, chunk = c & 31;
        int kb = chunk >> 4, j = chunk & 15;
        int gl = ((kb << 4) | (j ^ (row & 15))) * 8;
        int rowg = bm * 64 + row;
        hOff[i] = rowg * 1024 + gl;
        xOff[i] = rowg * XP + gl;
        useX[i] = (gl < 128);
        ldsOff[i] = (wave * 4 + i) * 512;
    }
    const int rowN = bn * 64 + wn * 16 + l16;
    const ushort* bpr0 = wpack + (size_t)rowN * KP2 + quad * 8;
    const ushort* bpr1 = bpr0 + (size_t)1024 * KP2;
    const ushort* bpr2 = bpr0 + (size_t)2048 * KP2;
    const float bir = b_ih[rowN],        bhr = b_hh[rowN];
    const float biz = b_ih[1024 + rowN], bhz = b_hh[1024 + rowN];
    const float bin_= b_ih[2048 + rowN], bhn = b_hh[2048 + rowN];

    float hprev[16];                                        // fp32 h state: registers!
#pragma unroll
    for (int i = 0; i < 16; ++i) hprev[i] = 0.f;

    // fc1 task: spread across all blocks. task = wave*256 + blk, 320 tasks (64 m x 5 n)
    const int task = wave * 256 + blk;
    const bool ftask = task < 320;
    const int fmt0 = (task & 63) * 16, fnt = task >> 6;
    const int jf = fnt * 16 + l16;                          // output col < 80
    const ushort* fbp = w1p + (size_t)jf * 1024 + quad * 8;
    const float fb1 = (jf < 69) ? fc1_b[jf] : 0.f;
    float xres[4], lacc[4];
#pragma unroll
    for (int r = 0; r < 4; ++r) {
        lacc[r] = 0.f;
        int m = fmt0 + quad * 4 + r;
        xres[r] = (ftask && jf < 69) ? enc[(size_t)m * 3450u + jf] : 0.f;
    }

    // ================= time loop =================
#pragma unroll 1
    for (int s = 0; s < 148; ++s) {
        const ushort* hsrc = (s & 1) ? hbf1 : hbf0;
        ushort*       hdst = (s & 1) ? hbf0 : hbf1;
        const ushort* xsrc = (s < 74) ? frames + (size_t)s * 131072u
                           : (s == 74 ? frames : (((s - 75) & 1) ? xbfB : xbfA));

        f32x4 accR[4], accZ[4], accNH[4], accNI[4];
#pragma unroll
        for (int i = 0; i < 4; ++i) {
            accR[i] = (f32x4){0.f,0.f,0.f,0.f}; accZ[i] = (f32x4){0.f,0.f,0.f,0.f};
            accNH[i] = (f32x4){0.f,0.f,0.f,0.f}; accNI[i] = (f32x4){0.f,0.f,0.f,0.f};
        }
        short8 bq[4][3];
#pragma unroll
        for (int kk = 0; kk < 4; ++kk) {
            const int off = (wk * 4 + kk) * 32;
            bq[kk][0] = *(const short8*)(bpr0 + off);
            bq[kk][1] = *(const short8*)(bpr1 + off);
            bq[kk][2] = *(const short8*)(bpr2 + off);
        }
#pragma unroll
        for (int i = 0; i < 4; ++i)                          // stage 0 (pure h)
            gld16(hsrc + hOff[i], &ldsA[0][ldsOff[i]]);
        __syncthreads();

#pragma unroll 1
        for (int st = 0; st < 5; ++st) {
            if (st < 4) {                                    // stage st+1 into other buf
                const int st1 = st + 1;
#pragma unroll
                for (int i = 0; i < 4; ++i) {
                    const ushort* g = (st1 < 4) ? hsrc + hOff[i] + st1 * 256
                                    : (useX[i] ? xsrc + xOff[i] : zpad);
                    gld16(g, &ldsA[st1 & 1][ldsOff[i]]);
                }
            }
            const ushort* ab = &ldsA[st & 1][0];
            if (st < 4) { GRU_COMPUTE(accNH, 1) } else { GRU_COMPUTE(accNI, 0) }
            __syncthreads();
        }

        // cross-wk reduction via LDS
        f32x4* red = (f32x4*)&ldsA[0][0];
        const int rslot = wn * 64 + lane;
        if (wk == 1) {
#pragma unroll
            for (int mt = 0; mt < 4; ++mt) {
                red[mt * 256 + rslot]        = accR[mt];
                red[1024 + mt * 256 + rslot] = accZ[mt];
            }
        }
        __syncthreads();
        if (wk == 0) {
#pragma unroll
            for (int mt = 0; mt < 4; ++mt) {
                accR[mt] += red[mt * 256 + rslot];
                accZ[mt] += red[1024 + mt * 256 + rslot];
            }
        }
        __syncthreads();
        if (wk == 1) {
#pragma unroll
            for (int mt = 0; mt < 4; ++mt) {
                red[mt * 256 + rslot]        = accNH[mt];
                red[1024 + mt * 256 + rslot] = accNI[mt];
            }
        }
        __syncthreads();
        if (wk == 0) {
#pragma unroll
            for (int mt = 0; mt < 4; ++mt) {
                accNH[mt] += red[mt * 256 + rslot];
                accNI[mt] += red[1024 + mt * 256 + rslot];
            }
            // epilogue: gates; h fp32 in regs; bf16 h via plain cached stores
#pragma unroll
            for (int mt = 0; mt < 4; ++mt) {
#pragma unroll
                for (int r = 0; r < 4; ++r) {
                    const int m = bm * 64 + mt * 16 + quad * 4 + r;
                    float gr = accR[mt][r] + bir + bhr;
                    float gz = accZ[mt][r] + biz + bhz;
                    float rg = 1.f / (1.f + __expf(-gr));
                    float zg = 1.f / (1.f + __expf(-gz));
                    float nx = accNI[mt][r] + bin_ + rg * (accNH[mt][r] + bhn);
                    nx = fminf(30.f, fmaxf(-30.f, nx));
                    float e  = __expf(-2.f * nx);
                    float ng = (1.f - e) / (1.f + e);
                    float hn = (1.f - zg) * ng + zg * hprev[mt * 4 + r];
                    hprev[mt * 4 + r] = hn;
                    ushort hb = f2bf(hn);
                    int ob = __shfl_xor((int)hb, 1, 64);
                    if ((lane & 1) == 0)
                        *(uint*)(hdst + (size_t)m * 1024 + rowN) =
                            (uint)hb | ((uint)ob << 16);
                }
            }
        }
        gridbar(ctrs, root, gen, blk);

        if (s >= 74) {                                       // fc1 interval (decode)
            const int d = s - 74;
            ushort* xbfout = (d & 1) ? xbfB : xbfA;
            if (ftask) {
                const ushort* ap = hdst + (size_t)(fmt0 + l16) * 1024 + quad * 8;
                short8 aw[8], bw[8];
#pragma unroll
                for (int p = 0; p < 8; ++p) {
                    aw[p] = *(const short8*)(ap + p * 32);
                    bw[p] = *(const short8*)(fbp + p * 32);
                }
                f32x4 facc = (f32x4){0.f, 0.f, 0.f, 0.f};
#pragma unroll
                for (int ks = 0; ks < 32; ++ks) {
                    short8 a = aw[ks & 7], b = bw[ks & 7];
                    if (ks < 24) {
                        aw[ks & 7] = *(const short8*)(ap + (ks + 8) * 32);
                        bw[ks & 7] = *(const short8*)(fbp + (ks + 8) * 32);
                    }
                    facc = MFMA(a, b, facc, 0, 0, 0);
                }
                const float w2v = (jf < 69) ? fc2_w[d * 69 + jf] : 0.f;
#pragma unroll
                for (int r = 0; r < 4; ++r) {
                    const int m = fmt0 + quad * 4 + r;
                    float o = facc[r] + xres[r] + fb1;
                    xres[r] = o;
                    lacc[r] += w2v * o;
                    ushort xb = f2bf(o);
                    int ob = __shfl_xor((int)xb, 1, 64);
                    if ((l16 & 1) == 0)
                        *(uint*)(xbfout + (size_t)m * XP + jf) =
                            (uint)xb | ((uint)ob << 16);
                }
            }
            gridbar(ctrs, root, gen, blk);
        }
    }
    // ================= logit + final =================
    if (ftask) {
#pragma unroll
        for (int r = 0; r < 4; ++r) {
            float lp = lacc[r];
            lp += __shfl_xor(lp, 8, 64);
            lp += __shfl_xor(lp, 4, 64);
            lp += __shfl_xor(lp, 2, 64);
            lp += __shfl_xor(lp, 1, 64);
            if (l16 == 0) atomicAdd(logit + fmt0 + quad * 4 + r, lp);
        }
    }
    gridbar(ctrs, root, gen, blk);
    if (blk == 0) {
        for (int i = t; i < 1024; i += 512) {
            float lg = logit[i];
            out[i] = 1.f / (1.f + __expf(-lg));
        }
    }
}

extern "C" void kernel_launch(void* const* d_in, const int* in_sizes, int n_in,
                              void* d_out, int out_size, void* d_ws, size_t ws_size,
                              hipStream_t stream)
{
    const float* enc   = (const float*)d_in[0];
    const float* dec   = (const float*)d_in[1];
    const float* w_ih  = (const float*)d_in[2];
    const float* w_hh  = (const float*)d_in[3];
    const float* b_ih  = (const float*)d_in[4];
    const float* b_hh  = (const float*)d_in[5];
    const float* fc1_w = (const float*)d_in[6];
    const float* fc1_b = (const float*)d_in[7];
    const float* fc2_w = (const float*)d_in[8];
    const float* fc2_b = (const float*)d_in[9];
    float* out = (float*)d_out;

    char* ws = (char*)d_ws;
    size_t off = 0;
    auto alloc = [&](size_t bytes) -> void* {
        void* p = ws + off; off += (bytes + 255) & ~(size_t)255; return p;
    };
    uint*   bar    = (uint*)  alloc(4096);
    ushort* wpack  = (ushort*)alloc((size_t)3072 * KP2 * 2);
    ushort* w1p    = (ushort*)alloc((size_t)80 * 1024 * 2);
    ushort* frames = (ushort*)alloc((size_t)74 * 1024 * XP * 2);
    ushort* hbf0   = (ushort*)alloc((size_t)1024 * 1024 * 2);
    ushort* hbf1   = (ushort*)alloc((size_t)1024 * 1024 * 2);
    ushort* xbfA   = (ushort*)alloc((size_t)1024 * XP * 2);
    ushort* xbfB   = (ushort*)alloc((size_t)1024 * XP * 2);
    float*  logit  = (float*) alloc((size_t)1024 * 4);
    ushort* zpad   = (ushort*)alloc(1024);

    hipMemsetAsync(bar, 0, 4096, stream);
    rnn_all<<<256, 512, 0, stream>>>(enc, dec, w_ih, w_hh, b_ih, b_hh,
                                     fc1_w, fc1_b, fc2_w, fc2_b, out,
                                     bar, wpack, w1p, frames,
                                     hbf0, hbf1, xbfA, xbfB, logit, zpad);
}